// Round 5
// baseline (298.222 us; speedup 1.0000x reference)
//
#include <hip/hip_runtime.h>
#include <hip/hip_bf16.h>

// Problem: N=10000, E=320000, FIN=512, FH=128, FOUT=40 (derived from in_sizes).
// Pipeline: convert X->bf16 (+fused deg count) + pack W1 (hi+lo bf16 split)
//   -> scan(rowptr,dinv) -> CSR fill
//   -> MFMA GEMM1 (bf16x2, fp32 accum, bf16 H0 out) -> gather-agg1(+bias+relu)
//   -> fp32 GEMM2 -> reg via row-parallel coalesced CSR scan -> gather-agg2 + log_softmax.
// reg identity: reg = sum over edges (a->b) of cnt(b->a); with CSR-by-dst,
// cnt(b->a) = #occurrences of b in row a. Row-parallel: wave per row b, lanes
// scan row a coalesced for each a in row b.

typedef __attribute__((ext_vector_type(8))) short short8;   // 8 x bf16 (4 VGPRs)
typedef __attribute__((ext_vector_type(4))) float float4v;  // MFMA C/D

__device__ __forceinline__ unsigned short f2bf(float f) {
    __hip_bfloat16 b = __float2bfloat16(f);
    return *reinterpret_cast<unsigned short*>(&b);
}
__device__ __forceinline__ float bf2f(unsigned short u) {
    __hip_bfloat16 b = *reinterpret_cast<__hip_bfloat16*>(&u);
    return __bfloat162float(b);
}

// ---- X fp32 -> bf16 (RNE), 4 elems/thread; fused in-degree count (same grid) ----
__global__ void k_convx_deg(const float* __restrict__ x, unsigned short* __restrict__ xh,
                            int total4, const int* __restrict__ dst, int E,
                            int* __restrict__ deg) {
    int i = blockIdx.x * blockDim.x + threadIdx.x;
    if (i < total4) {
        float4 v = ((const float4*)x)[i];
        ushort4 h;
        h.x = f2bf(v.x); h.y = f2bf(v.y); h.z = f2bf(v.z); h.w = f2bf(v.w);
        ((ushort4*)xh)[i] = h;
    }
    if (i < E) atomicAdd(&deg[dst[i]], 1);
}

// ---- pack W1[K][N] into MFMA B-fragment order, hi + lo residual ----
__global__ void k_packw(const float* __restrict__ W, unsigned short* __restrict__ Bh,
                        unsigned short* __restrict__ Bl, int KB, int NF, int Ndim) {
    int t = blockIdx.x * blockDim.x + threadIdx.x;
    if (t >= KB * NF * 64) return;
    int lane = t & 63;
    int f = (t >> 6) % NF;
    int kb = (t >> 6) / NF;
    int kbase = kb * 32 + (lane >> 4) * 8;
    int n = f * 16 + (lane & 15);
    unsigned short hj[8], lj[8];
#pragma unroll
    for (int j = 0; j < 8; j++) {
        float v = W[(size_t)(kbase + j) * Ndim + n];
        unsigned short hb = f2bf(v);
        hj[j] = hb;
        lj[j] = f2bf(v - bf2f(hb));
    }
    ushort4 h0 = {hj[0], hj[1], hj[2], hj[3]}, h1 = {hj[4], hj[5], hj[6], hj[7]};
    ushort4 l0 = {lj[0], lj[1], lj[2], lj[3]}, l1 = {lj[4], lj[5], lj[6], lj[7]};
    ((ushort4*)Bh)[t * 2] = h0; ((ushort4*)Bh)[t * 2 + 1] = h1;
    ((ushort4*)Bl)[t * 2] = l0; ((ushort4*)Bl)[t * 2 + 1] = l1;
}

// ---- MFMA GEMM1: H0[M][N](bf16) = Xh[M][K] @ W1 (bf16x2), N=NF*16, K=KB*32 ----
template <int NF, int KB>
__global__ void k_mfma_gemm1(const unsigned short* __restrict__ Xh,
                             const unsigned short* __restrict__ Bh,
                             const unsigned short* __restrict__ Bl,
                             unsigned short* __restrict__ H0, int M) {
    const int K = KB * 32, N = NF * 16;
    int w = threadIdx.x >> 6, lane = threadIdx.x & 63;
    int m0 = blockIdx.x * 64 + w * 16;
    if (m0 >= M) return;
    float4v acc[NF] = {};
    const short8* A = (const short8*)(Xh + (size_t)(m0 + (lane & 15)) * K) + (lane >> 4);
    const short8* BH = ((const short8*)Bh) + lane;
    const short8* BL = ((const short8*)Bl) + lane;
    for (int kb = 0; kb < KB; kb++) {
        short8 a = A[kb * 4];
#pragma unroll
        for (int f = 0; f < NF; f++) {
            short8 bh = BH[(kb * NF + f) * 64];
            short8 bl = BL[(kb * NF + f) * 64];
            acc[f] = __builtin_amdgcn_mfma_f32_16x16x32_bf16(a, bh, acc[f], 0, 0, 0);
            acc[f] = __builtin_amdgcn_mfma_f32_16x16x32_bf16(a, bl, acc[f], 0, 0, 0);
        }
    }
    int row = (lane >> 4) * 4, col = lane & 15;
#pragma unroll
    for (int f = 0; f < NF; f++)
#pragma unroll
        for (int r = 0; r < 4; r++)
            H0[(size_t)(m0 + row + r) * N + f * 16 + col] = f2bf(acc[f][r]);
}

// ---- single-block exclusive scan of deg -> rowptr; also dinv = rsqrt(deg+1) ----
__global__ void k_scan(const int* __restrict__ deg, int* __restrict__ rowptr,
                       float* __restrict__ dinv, int Nn) {
    __shared__ int part[256];
    int t = threadIdx.x;
    int per = (Nn + 255) / 256;
    int beg = t * per, lim = min(beg + per, Nn);
    int sum = 0;
    for (int i = beg; i < lim; i++) sum += deg[i];
    part[t] = sum;
    __syncthreads();
    for (int off = 1; off < 256; off <<= 1) {
        int v = (t >= off) ? part[t - off] : 0;
        __syncthreads();
        part[t] += v;
        __syncthreads();
    }
    int run = (t > 0) ? part[t - 1] : 0;
    for (int i = beg; i < lim; i++) {
        rowptr[i] = run;
        run += deg[i];
        dinv[i] = rsqrtf((float)deg[i] + 1.0f);  // +1 self-loop
    }
    if (t == 255) rowptr[Nn] = run;
}

// ---- scatter edges into CSR buckets ----
__global__ void k_fill(const int* __restrict__ src, const int* __restrict__ dst, int E,
                       const int* __restrict__ rowptr, int* __restrict__ cursor,
                       int* __restrict__ csr) {
    int e = blockIdx.x * blockDim.x + threadIdx.x;
    if (e >= E) return;
    int d = dst[e];
    int pos = atomicAdd(&cursor[d], 1);
    csr[rowptr[d] + pos] = src[e];
}

// ---- reg, row-parallel: wave per row b; for each a in row b, lanes scan row a ----
__global__ void k_reg_row(const int* __restrict__ rowptr, const int* __restrict__ csr,
                          int Nn, float* __restrict__ regp) {
    int b = (blockIdx.x * blockDim.x + threadIdx.x) >> 6;
    int lane = threadIdx.x & 63;
    if (b >= Nn) return;
    int beg = rowptr[b], end = rowptr[b + 1];
    int c = 0;
    for (int j = beg; j < end; j++) {
        int a = csr[j];                      // wave-uniform (same addr all lanes)
        int ab = rowptr[a], ae = rowptr[a + 1];
        for (int k = ab + lane; k < ae; k += 64)
            c += (csr[k] == b) ? 1 : 0;      // coalesced
    }
#pragma unroll
    for (int off = 32; off; off >>= 1) c += __shfl_xor(c, off, 64);
    if (lane == 0 && c) atomicAdd(regp, (float)c);
}

// ---- fp32 tiled GEMM (used for GEMM2): C[M,N] = A[M,K] @ B[K,N] ----
__global__ void gemm64(const float* __restrict__ A, const float* __restrict__ B,
                       float* __restrict__ C, int M, int N, int K) {
    __shared__ float As[16][64];
    __shared__ float Bs[16][64];
    int row0 = blockIdx.x * 64, col0 = blockIdx.y * 64;
    int t = threadIdx.x;
    int tx = t & 15, ty = t >> 4;
    float acc[4][4] = {};
    for (int k0 = 0; k0 < K; k0 += 16) {
#pragma unroll
        for (int i = 0; i < 4; i++) {
            int idx = t + i * 256;
            int m = idx >> 4, kk = idx & 15;
            float va = 0.f;
            if (row0 + m < M) va = A[(size_t)(row0 + m) * K + k0 + kk];
            As[kk][m] = va;
            int k2 = idx >> 6, n2 = idx & 63;
            float vb = 0.f;
            if (col0 + n2 < N) vb = B[(size_t)(k0 + k2) * N + col0 + n2];
            Bs[k2][n2] = vb;
        }
        __syncthreads();
#pragma unroll
        for (int kk = 0; kk < 16; kk++) {
            float a[4], b[4];
#pragma unroll
            for (int i = 0; i < 4; i++) a[i] = As[kk][ty * 4 + i];
#pragma unroll
            for (int j = 0; j < 4; j++) b[j] = Bs[kk][tx * 4 + j];
#pragma unroll
            for (int i = 0; i < 4; i++)
#pragma unroll
                for (int j = 0; j < 4; j++) acc[i][j] += a[i] * b[j];
        }
        __syncthreads();
    }
#pragma unroll
    for (int i = 0; i < 4; i++) {
        int m = row0 + ty * 4 + i;
        if (m >= M) continue;
#pragma unroll
        for (int j = 0; j < 4; j++) {
            int n = col0 + tx * 4 + j;
            if (n < N) C[(size_t)m * N + n] = acc[i][j];
        }
    }
}

// ---- layer-1 gather aggregation over bf16 H0, wave per dst node, fused bias+relu ----
__global__ void k_agg1(const int* __restrict__ rowptr, const int* __restrict__ csr,
                       const float* __restrict__ dinv, const unsigned short* __restrict__ H,
                       const float* __restrict__ b1, float* __restrict__ out, int Nn) {
    int wid = (blockIdx.x * blockDim.x + threadIdx.x) >> 6;
    int lane = threadIdx.x & 63;
    if (wid >= Nn) return;
    float dd = dinv[wid];
    const unsigned* H2 = (const unsigned*)H;   // bf16x2 per lane (4B)
    unsigned ph = H2[(size_t)wid * 64 + lane];
    float sw = dd * dd;
    float accx = bf2f((unsigned short)(ph & 0xffff)) * sw;
    float accy = bf2f((unsigned short)(ph >> 16)) * sw;   // self-loop
    int beg = rowptr[wid], end = rowptr[wid + 1];
    int j = beg;
    for (; j + 1 < end; j += 2) {
        int s0 = csr[j], s1 = csr[j + 1];
        float w0 = dinv[s0] * dd, w1 = dinv[s1] * dd;
        unsigned p0 = H2[(size_t)s0 * 64 + lane];
        unsigned p1 = H2[(size_t)s1 * 64 + lane];
        accx += w0 * bf2f((unsigned short)(p0 & 0xffff)) + w1 * bf2f((unsigned short)(p1 & 0xffff));
        accy += w0 * bf2f((unsigned short)(p0 >> 16))   + w1 * bf2f((unsigned short)(p1 >> 16));
    }
    if (j < end) {
        int s0 = csr[j];
        float w0 = dinv[s0] * dd;
        unsigned p0 = H2[(size_t)s0 * 64 + lane];
        accx += w0 * bf2f((unsigned short)(p0 & 0xffff));
        accy += w0 * bf2f((unsigned short)(p0 >> 16));
    }
    float2 bb = ((const float2*)b1)[lane];
    float vx = accx + bb.x, vy = accy + bb.y;
    float2 o;
    o.x = vx > 0.f ? vx : 0.f;
    o.y = vy > 0.f ? vy : 0.f;
    ((float2*)out)[(size_t)wid * 64 + lane] = o;
}

// ---- layer-2 gather aggregation + bias + log_softmax, wave per dst node ----
__global__ void k_agg2_lsm(const int* __restrict__ rowptr, const int* __restrict__ csr,
                           const float* __restrict__ dinv, const float* __restrict__ LG,
                           const float* __restrict__ b2, const float* __restrict__ regp,
                           float* __restrict__ out, int Nn, int F) {
    int wid = (blockIdx.x * blockDim.x + threadIdx.x) >> 6;
    int lane = threadIdx.x & 63;
    if (wid >= Nn) return;
    float dd = dinv[wid];
    bool act = lane < F;
    float acc = act ? LG[(size_t)wid * F + lane] * dd * dd : 0.f;  // self-loop
    int beg = rowptr[wid], end = rowptr[wid + 1];
    int j = beg;
    for (; j + 1 < end; j += 2) {
        int s0 = csr[j], s1 = csr[j + 1];
        float w0 = dinv[s0] * dd, w1 = dinv[s1] * dd;
        float a0 = act ? LG[(size_t)s0 * F + lane] : 0.f;
        float a1 = act ? LG[(size_t)s1 * F + lane] : 0.f;
        acc += w0 * a0 + w1 * a1;
    }
    if (j < end) {
        int s0 = csr[j];
        float w0 = dinv[s0] * dd;
        float a0 = act ? LG[(size_t)s0 * F + lane] : 0.f;
        acc += w0 * a0;
    }
    float v = act ? acc + b2[lane] : -1e30f;
    float m = v;
#pragma unroll
    for (int off = 32; off; off >>= 1) m = fmaxf(m, __shfl_xor(m, off, 64));
    float ex = act ? expf(v - m) : 0.f;
    float ssum = ex;
#pragma unroll
    for (int off = 32; off; off >>= 1) ssum += __shfl_xor(ssum, off, 64);
    if (act) out[(size_t)wid * F + lane] = v - m - logf(ssum);
    if (wid == 0 && lane == 0) out[(size_t)Nn * F] = regp[0];
}

extern "C" void kernel_launch(void* const* d_in, const int* in_sizes, int n_in,
                              void* d_out, int out_size, void* d_ws, size_t ws_size,
                              hipStream_t stream) {
    const float* x  = (const float*)d_in[0];
    const int*   ei = (const int*)d_in[1];
    const float* W1 = (const float*)d_in[2];
    const float* b1 = (const float*)d_in[3];
    const float* W2 = (const float*)d_in[4];
    const float* b2 = (const float*)d_in[5];
    float* out = (float*)d_out;

    const int FH   = in_sizes[3];            // 128
    const int FOUT = in_sizes[5];            // 40
    const int FIN  = in_sizes[2] / FH;       // 512
    const int Nn   = in_sizes[0] / FIN;      // 10000
    const int E    = in_sizes[1] / 2;        // 320000
    const int* src = ei;
    const int* dst = ei + E;
    const int KB = FIN / 32, NF = FH / 16;   // 16, 8

    // ---- workspace layout ----
    // zero-init region (contiguous): deg, cursor, regp(+pad)
    int*      deg    = (int*)d_ws;                        // Nn
    int*      cursor = deg + Nn;                          // Nn
    float*    regp   = (float*)(cursor + Nn);             // 1 (+15 pad)
    size_t zero_bytes = ((size_t)Nn + Nn + 16) * 4;
    // non-init region:
    int*      rowptr = (int*)(regp + 16);                 // Nn+1
    int*      csr    = rowptr + Nn + 1;                   // E
    float*    dinv   = (float*)(csr + E);                 // Nn
    float*    AGG1   = dinv + Nn;                         // Nn*FH fp32
    float*    LG0    = AGG1 + (size_t)Nn * FH;            // Nn*FOUT fp32
    unsigned short* Xh  = (unsigned short*)(LG0 + (size_t)Nn * FOUT);  // Nn*FIN bf16
    unsigned short* H0b = Xh + (size_t)Nn * FIN;          // Nn*FH bf16
    unsigned short* Bh  = H0b + (size_t)Nn * FH;          // KB*NF*64*8 bf16
    unsigned short* Bl  = Bh + (size_t)KB * NF * 64 * 8;  // same

    hipMemsetAsync(d_ws, 0, zero_bytes, stream);

    // convert X + deg count (fused, same 320k-thread grid) ; pack W1
    int total4 = Nn * FIN / 4;
    k_convx_deg<<<(total4 + 255) / 256, 256, 0, stream>>>(x, Xh, total4, dst, E, deg);
    k_packw<<<(KB * NF * 64 + 255) / 256, 256, 0, stream>>>(W1, Bh, Bl, KB, NF, FH);

    k_scan<<<1, 256, 0, stream>>>(deg, rowptr, dinv, Nn);
    k_fill<<<(E + 255) / 256, 256, 0, stream>>>(src, dst, E, rowptr, cursor, csr);

    // H0(bf16) = X @ W1 via MFMA bf16x2
    k_mfma_gemm1<8, 16><<<(Nn + 63) / 64, 256, 0, stream>>>(Xh, Bh, Bl, H0b, Nn);
    // AGG1 = relu(gather(H0) + b1), wave per node
    k_agg1<<<(Nn * 64 + 255) / 256, 256, 0, stream>>>(rowptr, csr, dinv, H0b, b1, AGG1, Nn);
    // LG0 = AGG1 @ W2 (fp32 vector GEMM)
    gemm64<<<dim3((Nn + 63) / 64, (FOUT + 63) / 64), 256, 0, stream>>>(AGG1, W2, LG0, Nn, FOUT, FH);
    // reg via row-parallel coalesced CSR scan (must precede k_agg2_lsm)
    k_reg_row<<<(Nn * 64 + 255) / 256, 256, 0, stream>>>(rowptr, csr, Nn, regp);
    // out = log_softmax(gather(LG0) + b2), reg -> out[Nn*FOUT]
    k_agg2_lsm<<<(Nn * 64 + 255) / 256, 256, 0, stream>>>(rowptr, csr, dinv, LG0, b2, regp, out, Nn, FOUT);
}

// Round 6
// 251.761 us; speedup vs baseline: 1.1845x; 1.1845x over previous
//
#include <hip/hip_runtime.h>
#include <hip/hip_bf16.h>

// Problem: N=10000, E=320000, FIN=512, FH=128, FOUT=40 (derived from in_sizes).
// Pipeline: convert X->bf16 (+fused deg count) + pack W1 (hi+lo bf16 split)
//   -> scan(rowptr,dinv) -> CSR fill (ushort node ids)
//   -> MFMA GEMM1 (bf16x2, fp32 accum, bf16 H0 out) -> gather-agg1(+bias+relu)
//   -> fp32 GEMM2 -> reg via edge-parallel vectorized CSR scan -> gather-agg2 + log_softmax.
// reg identity: reg = sum over edges e=(s,d) of A[d,s]; with CSR-by-dst (row i = srcs
// of edges into i), A[d,s] = #occurrences of value d in row s. Edge-parallel, each
// lane scans its row as 8B uint2 chunks (4 ushort compares per load) for ILP.

typedef __attribute__((ext_vector_type(8))) short short8;   // 8 x bf16 (4 VGPRs)
typedef __attribute__((ext_vector_type(4))) float float4v;  // MFMA C/D

__device__ __forceinline__ unsigned short f2bf(float f) {
    __hip_bfloat16 b = __float2bfloat16(f);
    return *reinterpret_cast<unsigned short*>(&b);
}
__device__ __forceinline__ float bf2f(unsigned short u) {
    __hip_bfloat16 b = *reinterpret_cast<__hip_bfloat16*>(&u);
    return __bfloat162float(b);
}

// ---- X fp32 -> bf16 (RNE), 4 elems/thread; fused in-degree count (same grid) ----
__global__ void k_convx_deg(const float* __restrict__ x, unsigned short* __restrict__ xh,
                            int total4, const int* __restrict__ dst, int E,
                            int* __restrict__ deg) {
    int i = blockIdx.x * blockDim.x + threadIdx.x;
    if (i < total4) {
        float4 v = ((const float4*)x)[i];
        ushort4 h;
        h.x = f2bf(v.x); h.y = f2bf(v.y); h.z = f2bf(v.z); h.w = f2bf(v.w);
        ((ushort4*)xh)[i] = h;
    }
    if (i < E) atomicAdd(&deg[dst[i]], 1);
}

// ---- pack W1[K][N] into MFMA B-fragment order, hi + lo residual ----
__global__ void k_packw(const float* __restrict__ W, unsigned short* __restrict__ Bh,
                        unsigned short* __restrict__ Bl, int KB, int NF, int Ndim) {
    int t = blockIdx.x * blockDim.x + threadIdx.x;
    if (t >= KB * NF * 64) return;
    int lane = t & 63;
    int f = (t >> 6) % NF;
    int kb = (t >> 6) / NF;
    int kbase = kb * 32 + (lane >> 4) * 8;
    int n = f * 16 + (lane & 15);
    unsigned short hj[8], lj[8];
#pragma unroll
    for (int j = 0; j < 8; j++) {
        float v = W[(size_t)(kbase + j) * Ndim + n];
        unsigned short hb = f2bf(v);
        hj[j] = hb;
        lj[j] = f2bf(v - bf2f(hb));
    }
    ushort4 h0 = {hj[0], hj[1], hj[2], hj[3]}, h1 = {hj[4], hj[5], hj[6], hj[7]};
    ushort4 l0 = {lj[0], lj[1], lj[2], lj[3]}, l1 = {lj[4], lj[5], lj[6], lj[7]};
    ((ushort4*)Bh)[t * 2] = h0; ((ushort4*)Bh)[t * 2 + 1] = h1;
    ((ushort4*)Bl)[t * 2] = l0; ((ushort4*)Bl)[t * 2 + 1] = l1;
}

// ---- MFMA GEMM1: H0[M][N](bf16) = Xh[M][K] @ W1 (bf16x2), N=NF*16, K=KB*32 ----
template <int NF, int KB>
__global__ void k_mfma_gemm1(const unsigned short* __restrict__ Xh,
                             const unsigned short* __restrict__ Bh,
                             const unsigned short* __restrict__ Bl,
                             unsigned short* __restrict__ H0, int M) {
    const int K = KB * 32, N = NF * 16;
    int w = threadIdx.x >> 6, lane = threadIdx.x & 63;
    int m0 = blockIdx.x * 64 + w * 16;
    if (m0 >= M) return;
    float4v acc[NF] = {};
    const short8* A = (const short8*)(Xh + (size_t)(m0 + (lane & 15)) * K) + (lane >> 4);
    const short8* BH = ((const short8*)Bh) + lane;
    const short8* BL = ((const short8*)Bl) + lane;
    for (int kb = 0; kb < KB; kb++) {
        short8 a = A[kb * 4];
#pragma unroll
        for (int f = 0; f < NF; f++) {
            short8 bh = BH[(kb * NF + f) * 64];
            short8 bl = BL[(kb * NF + f) * 64];
            acc[f] = __builtin_amdgcn_mfma_f32_16x16x32_bf16(a, bh, acc[f], 0, 0, 0);
            acc[f] = __builtin_amdgcn_mfma_f32_16x16x32_bf16(a, bl, acc[f], 0, 0, 0);
        }
    }
    int row = (lane >> 4) * 4, col = lane & 15;
#pragma unroll
    for (int f = 0; f < NF; f++)
#pragma unroll
        for (int r = 0; r < 4; r++)
            H0[(size_t)(m0 + row + r) * N + f * 16 + col] = f2bf(acc[f][r]);
}

// ---- single-block exclusive scan of deg -> rowptr; also dinv = rsqrt(deg+1) ----
__global__ void k_scan(const int* __restrict__ deg, int* __restrict__ rowptr,
                       float* __restrict__ dinv, int Nn) {
    __shared__ int part[256];
    int t = threadIdx.x;
    int per = (Nn + 255) / 256;
    int beg = t * per, lim = min(beg + per, Nn);
    int sum = 0;
    for (int i = beg; i < lim; i++) sum += deg[i];
    part[t] = sum;
    __syncthreads();
    for (int off = 1; off < 256; off <<= 1) {
        int v = (t >= off) ? part[t - off] : 0;
        __syncthreads();
        part[t] += v;
        __syncthreads();
    }
    int run = (t > 0) ? part[t - 1] : 0;
    for (int i = beg; i < lim; i++) {
        rowptr[i] = run;
        run += deg[i];
        dinv[i] = rsqrtf((float)deg[i] + 1.0f);  // +1 self-loop
    }
    if (t == 255) rowptr[Nn] = run;
}

// ---- scatter edges into CSR buckets (ushort ids) ----
__global__ void k_fill(const int* __restrict__ src, const int* __restrict__ dst, int E,
                       const int* __restrict__ rowptr, int* __restrict__ cursor,
                       unsigned short* __restrict__ csr) {
    int e = blockIdx.x * blockDim.x + threadIdx.x;
    if (e >= E) return;
    int d = dst[e];
    int pos = atomicAdd(&cursor[d], 1);
    csr[rowptr[d] + pos] = (unsigned short)src[e];
}

// ---- reg, edge-parallel: lane e scans row src[e] for dst[e], 4 ushorts per 8B load ----
__global__ void k_reg_edge(const int* __restrict__ src, const int* __restrict__ dst, int E,
                           const int* __restrict__ rowptr, const unsigned short* __restrict__ csr,
                           float* __restrict__ regp) {
    int e = blockIdx.x * blockDim.x + threadIdx.x;
    int c = 0;
    if (e < E) {
        int s = src[e];
        unsigned d = (unsigned)dst[e];
        int beg = rowptr[s], end = rowptr[s + 1];
        int i0 = beg & ~3;                      // 8B-aligned start
        for (int i = i0; i < end; i += 4) {
            uint2 v = *(const uint2*)(csr + i); // 4 ushorts
            int idx0 = i, idx1 = i + 1, idx2 = i + 2, idx3 = i + 3;
            c += ((v.x & 0xffffu) == d && idx0 >= beg && idx0 < end) ? 1 : 0;
            c += ((v.x >> 16)     == d && idx1 >= beg && idx1 < end) ? 1 : 0;
            c += ((v.y & 0xffffu) == d && idx2 >= beg && idx2 < end) ? 1 : 0;
            c += ((v.y >> 16)     == d && idx3 >= beg && idx3 < end) ? 1 : 0;
        }
    }
#pragma unroll
    for (int off = 32; off; off >>= 1) c += __shfl_xor(c, off, 64);
    if ((threadIdx.x & 63) == 0 && c) atomicAdd(regp, (float)c);
}

// ---- fp32 tiled GEMM (used for GEMM2): C[M,N] = A[M,K] @ B[K,N] ----
__global__ void gemm64(const float* __restrict__ A, const float* __restrict__ B,
                       float* __restrict__ C, int M, int N, int K) {
    __shared__ float As[16][64];
    __shared__ float Bs[16][64];
    int row0 = blockIdx.x * 64, col0 = blockIdx.y * 64;
    int t = threadIdx.x;
    int tx = t & 15, ty = t >> 4;
    float acc[4][4] = {};
    for (int k0 = 0; k0 < K; k0 += 16) {
#pragma unroll
        for (int i = 0; i < 4; i++) {
            int idx = t + i * 256;
            int m = idx >> 4, kk = idx & 15;
            float va = 0.f;
            if (row0 + m < M) va = A[(size_t)(row0 + m) * K + k0 + kk];
            As[kk][m] = va;
            int k2 = idx >> 6, n2 = idx & 63;
            float vb = 0.f;
            if (col0 + n2 < N) vb = B[(size_t)(k0 + k2) * N + col0 + n2];
            Bs[k2][n2] = vb;
        }
        __syncthreads();
#pragma unroll
        for (int kk = 0; kk < 16; kk++) {
            float a[4], b[4];
#pragma unroll
            for (int i = 0; i < 4; i++) a[i] = As[kk][ty * 4 + i];
#pragma unroll
            for (int j = 0; j < 4; j++) b[j] = Bs[kk][tx * 4 + j];
#pragma unroll
            for (int i = 0; i < 4; i++)
#pragma unroll
                for (int j = 0; j < 4; j++) acc[i][j] += a[i] * b[j];
        }
        __syncthreads();
    }
#pragma unroll
    for (int i = 0; i < 4; i++) {
        int m = row0 + ty * 4 + i;
        if (m >= M) continue;
#pragma unroll
        for (int j = 0; j < 4; j++) {
            int n = col0 + tx * 4 + j;
            if (n < N) C[(size_t)m * N + n] = acc[i][j];
        }
    }
}

// ---- layer-1 gather aggregation over bf16 H0, wave per dst node, fused bias+relu ----
__global__ void k_agg1(const int* __restrict__ rowptr, const unsigned short* __restrict__ csr,
                       const float* __restrict__ dinv, const unsigned short* __restrict__ H,
                       const float* __restrict__ b1, float* __restrict__ out, int Nn) {
    int wid = (blockIdx.x * blockDim.x + threadIdx.x) >> 6;
    int lane = threadIdx.x & 63;
    if (wid >= Nn) return;
    float dd = dinv[wid];
    const unsigned* H2 = (const unsigned*)H;   // bf16x2 per lane (4B)
    unsigned ph = H2[(size_t)wid * 64 + lane];
    float sw = dd * dd;
    float accx = bf2f((unsigned short)(ph & 0xffff)) * sw;
    float accy = bf2f((unsigned short)(ph >> 16)) * sw;   // self-loop
    int beg = rowptr[wid], end = rowptr[wid + 1];
    int j = beg;
    for (; j + 3 < end; j += 4) {
        int s0 = csr[j], s1 = csr[j + 1], s2 = csr[j + 2], s3 = csr[j + 3];
        float w0 = dinv[s0] * dd, w1 = dinv[s1] * dd;
        float w2 = dinv[s2] * dd, w3 = dinv[s3] * dd;
        unsigned p0 = H2[(size_t)s0 * 64 + lane];
        unsigned p1 = H2[(size_t)s1 * 64 + lane];
        unsigned p2 = H2[(size_t)s2 * 64 + lane];
        unsigned p3 = H2[(size_t)s3 * 64 + lane];
        accx += w0 * bf2f((unsigned short)(p0 & 0xffff)) + w1 * bf2f((unsigned short)(p1 & 0xffff));
        accy += w0 * bf2f((unsigned short)(p0 >> 16))   + w1 * bf2f((unsigned short)(p1 >> 16));
        accx += w2 * bf2f((unsigned short)(p2 & 0xffff)) + w3 * bf2f((unsigned short)(p3 & 0xffff));
        accy += w2 * bf2f((unsigned short)(p2 >> 16))   + w3 * bf2f((unsigned short)(p3 >> 16));
    }
    for (; j < end; j++) {
        int s0 = csr[j];
        float w0 = dinv[s0] * dd;
        unsigned p0 = H2[(size_t)s0 * 64 + lane];
        accx += w0 * bf2f((unsigned short)(p0 & 0xffff));
        accy += w0 * bf2f((unsigned short)(p0 >> 16));
    }
    float2 bb = ((const float2*)b1)[lane];
    float vx = accx + bb.x, vy = accy + bb.y;
    float2 o;
    o.x = vx > 0.f ? vx : 0.f;
    o.y = vy > 0.f ? vy : 0.f;
    ((float2*)out)[(size_t)wid * 64 + lane] = o;
}

// ---- layer-2 gather aggregation + bias + log_softmax, wave per dst node ----
__global__ void k_agg2_lsm(const int* __restrict__ rowptr, const unsigned short* __restrict__ csr,
                           const float* __restrict__ dinv, const float* __restrict__ LG,
                           const float* __restrict__ b2, const float* __restrict__ regp,
                           float* __restrict__ out, int Nn, int F) {
    int wid = (blockIdx.x * blockDim.x + threadIdx.x) >> 6;
    int lane = threadIdx.x & 63;
    if (wid >= Nn) return;
    float dd = dinv[wid];
    bool act = lane < F;
    float acc = act ? LG[(size_t)wid * F + lane] * dd * dd : 0.f;  // self-loop
    int beg = rowptr[wid], end = rowptr[wid + 1];
    int j = beg;
    for (; j + 3 < end; j += 4) {
        int s0 = csr[j], s1 = csr[j + 1], s2 = csr[j + 2], s3 = csr[j + 3];
        float w0 = dinv[s0] * dd, w1 = dinv[s1] * dd;
        float w2 = dinv[s2] * dd, w3 = dinv[s3] * dd;
        float a0 = act ? LG[(size_t)s0 * F + lane] : 0.f;
        float a1 = act ? LG[(size_t)s1 * F + lane] : 0.f;
        float a2 = act ? LG[(size_t)s2 * F + lane] : 0.f;
        float a3 = act ? LG[(size_t)s3 * F + lane] : 0.f;
        acc += w0 * a0 + w1 * a1 + w2 * a2 + w3 * a3;
    }
    for (; j < end; j++) {
        int s0 = csr[j];
        float w0 = dinv[s0] * dd;
        float a0 = act ? LG[(size_t)s0 * F + lane] : 0.f;
        acc += w0 * a0;
    }
    float v = act ? acc + b2[lane] : -1e30f;
    float m = v;
#pragma unroll
    for (int off = 32; off; off >>= 1) m = fmaxf(m, __shfl_xor(m, off, 64));
    float ex = act ? expf(v - m) : 0.f;
    float ssum = ex;
#pragma unroll
    for (int off = 32; off; off >>= 1) ssum += __shfl_xor(ssum, off, 64);
    if (act) out[(size_t)wid * F + lane] = v - m - logf(ssum);
    if (wid == 0 && lane == 0) out[(size_t)Nn * F] = regp[0];
}

extern "C" void kernel_launch(void* const* d_in, const int* in_sizes, int n_in,
                              void* d_out, int out_size, void* d_ws, size_t ws_size,
                              hipStream_t stream) {
    const float* x  = (const float*)d_in[0];
    const int*   ei = (const int*)d_in[1];
    const float* W1 = (const float*)d_in[2];
    const float* b1 = (const float*)d_in[3];
    const float* W2 = (const float*)d_in[4];
    const float* b2 = (const float*)d_in[5];
    float* out = (float*)d_out;

    const int FH   = in_sizes[3];            // 128
    const int FOUT = in_sizes[5];            // 40
    const int FIN  = in_sizes[2] / FH;       // 512
    const int Nn   = in_sizes[0] / FIN;      // 10000
    const int E    = in_sizes[1] / 2;        // 320000
    const int* src = ei;
    const int* dst = ei + E;
    const int KB = FIN / 32, NF = FH / 16;   // 16, 8

    // ---- workspace layout (8B alignment maintained throughout) ----
    // zero-init region (contiguous): deg, cursor, regp(+pad)
    int*      deg    = (int*)d_ws;                        // Nn
    int*      cursor = deg + Nn;                          // Nn
    float*    regp   = (float*)(cursor + Nn);             // 1 (+15 pad)
    size_t zero_bytes = ((size_t)Nn + Nn + 16) * 4;
    // non-init region:
    int*      rowptr = (int*)(regp + 16);                 // Nn+2 (padded, 8B align)
    unsigned short* csr = (unsigned short*)(rowptr + Nn + 2);  // E+8 ushort (8B-aligned base)
    float*    dinv   = (float*)(csr + E + 8);             // Nn
    float*    AGG1   = dinv + Nn;                         // Nn*FH fp32
    float*    LG0    = AGG1 + (size_t)Nn * FH;            // Nn*FOUT fp32
    unsigned short* Xh  = (unsigned short*)(LG0 + (size_t)Nn * FOUT);  // Nn*FIN bf16
    unsigned short* H0b = Xh + (size_t)Nn * FIN;          // Nn*FH bf16
    unsigned short* Bh  = H0b + (size_t)Nn * FH;          // KB*NF*64*8 bf16
    unsigned short* Bl  = Bh + (size_t)KB * NF * 64 * 8;  // same

    hipMemsetAsync(d_ws, 0, zero_bytes, stream);

    // convert X + deg count (fused, same grid) ; pack W1
    int total4 = Nn * FIN / 4;
    k_convx_deg<<<(total4 + 255) / 256, 256, 0, stream>>>(x, Xh, total4, dst, E, deg);
    k_packw<<<(KB * NF * 64 + 255) / 256, 256, 0, stream>>>(W1, Bh, Bl, KB, NF, FH);

    k_scan<<<1, 256, 0, stream>>>(deg, rowptr, dinv, Nn);
    k_fill<<<(E + 255) / 256, 256, 0, stream>>>(src, dst, E, rowptr, cursor, csr);

    // H0(bf16) = X @ W1 via MFMA bf16x2
    k_mfma_gemm1<8, 16><<<(Nn + 63) / 64, 256, 0, stream>>>(Xh, Bh, Bl, H0b, Nn);
    // AGG1 = relu(gather(H0) + b1), wave per node
    k_agg1<<<(Nn * 64 + 255) / 256, 256, 0, stream>>>(rowptr, csr, dinv, H0b, b1, AGG1, Nn);
    // LG0 = AGG1 @ W2 (fp32 vector GEMM)
    gemm64<<<dim3((Nn + 63) / 64, (FOUT + 63) / 64), 256, 0, stream>>>(AGG1, W2, LG0, Nn, FOUT, FH);
    // reg via edge-parallel vectorized CSR scan (must precede k_agg2_lsm)
    k_reg_edge<<<(E + 255) / 256, 256, 0, stream>>>(src, dst, E, rowptr, csr, regp);
    // out = log_softmax(gather(LG0) + b2), reg -> out[Nn*FOUT]
    k_agg2_lsm<<<(Nn * 64 + 255) / 256, 256, 0, stream>>>(rowptr, csr, dinv, LG0, b2, regp, out, Nn, FOUT);
}

// Round 7
// 201.290 us; speedup vs baseline: 1.4816x; 1.2507x over previous
//
#include <hip/hip_runtime.h>
#include <hip/hip_bf16.h>

// Problem: N=10000, E=320000, FIN=512, FH=128, FOUT=40 (derived from in_sizes).
// Padded-CSR pipeline (CAP=128 slots/node; deg ~ Poisson(32), overflow impossible):
//  1. k_prep  : zero cnt/regp + X->bf16 + pack W1(hi/lo) + pack W2(hi/lo, N padded 40->48)
//  2. k_fill  : one atomicAdd per edge = position alloc AND degree count; csr[d*CAP+pos]=src
//  3. k_mfma_gemm1 : H0(bf16) = Xbf @ W1 (bf16x2 hi+lo, fp32 accum)
//  4. k_agg1_reg   : [agg blocks] AGG1b(bf16) = relu(gather(H0)+b1), dinv on the fly
//                    [reg blocks] reg += count of dst[e] in csr-row src[e] (A[d,s] identity)
//  5. k_mfma_gemm2 : LG(fp32, stride 48) = AGG1b @ W2 (bf16 A, hi+lo B)
//  6. k_agg2_lsm   : out = log_softmax(gather(LG)+b2); out[N*F] = reg
// reg identity: reg = sum_{(s,d) in E} A[d,s]; CSR-by-dst row s holds srcs of edges
// into s, so A[d,s] = #occurrences of d in row s.

#define CAP 128

typedef __attribute__((ext_vector_type(8))) short short8;   // 8 x bf16 (4 VGPRs)
typedef __attribute__((ext_vector_type(4))) float float4v;  // MFMA C/D

__device__ __forceinline__ unsigned short f2bf(float f) {
    __hip_bfloat16 b = __float2bfloat16(f);
    return *reinterpret_cast<unsigned short*>(&b);
}
__device__ __forceinline__ float bf2f(unsigned short u) {
    __hip_bfloat16 b = *reinterpret_cast<__hip_bfloat16*>(&u);
    return __bfloat162float(b);
}

// ---- fused prep: zero cnt/regp | conv X->bf16 | pack W1 hi/lo | pack W2 hi/lo ----
__global__ void k_prep(const float* __restrict__ x, unsigned short* __restrict__ xh, int total4,
                       const float* __restrict__ W1, unsigned short* __restrict__ Bh1,
                       unsigned short* __restrict__ Bl1,
                       const float* __restrict__ W2, unsigned short* __restrict__ Bh2,
                       unsigned short* __restrict__ Bl2,
                       int* __restrict__ zbase, int zints,
                       int convB, int p1B, int p2B) {
    int b = blockIdx.x;
    if (b < convB) {
        int i = b * 256 + threadIdx.x;
        if (i < total4) {
            float4 v = ((const float4*)x)[i];
            ushort4 h;
            h.x = f2bf(v.x); h.y = f2bf(v.y); h.z = f2bf(v.z); h.w = f2bf(v.w);
            ((ushort4*)xh)[i] = h;
        }
        return;
    }
    b -= convB;
    if (b < p1B) {   // pack W1: KB=16, NF=8, N=128
        int t = b * 256 + threadIdx.x;
        int lane = t & 63;
        int f = (t >> 6) % 8;
        int kb = (t >> 6) / 8;
        int kbase = kb * 32 + (lane >> 4) * 8;
        int n = f * 16 + (lane & 15);
        unsigned short hj[8], lj[8];
#pragma unroll
        for (int j = 0; j < 8; j++) {
            float v = W1[(size_t)(kbase + j) * 128 + n];
            unsigned short hb = f2bf(v);
            hj[j] = hb;
            lj[j] = f2bf(v - bf2f(hb));
        }
        ushort4 h0 = {hj[0], hj[1], hj[2], hj[3]}, h1 = {hj[4], hj[5], hj[6], hj[7]};
        ushort4 l0 = {lj[0], lj[1], lj[2], lj[3]}, l1 = {lj[4], lj[5], lj[6], lj[7]};
        ((ushort4*)Bh1)[t * 2] = h0; ((ushort4*)Bh1)[t * 2 + 1] = h1;
        ((ushort4*)Bl1)[t * 2] = l0; ((ushort4*)Bl1)[t * 2 + 1] = l1;
        return;
    }
    b -= p1B;
    if (b < p2B) {   // pack W2: KB=4, NF=3 (48 padded, real N=40)
        int t = b * 256 + threadIdx.x;
        if (t >= 4 * 3 * 64) return;
        int lane = t & 63;
        int f = (t >> 6) % 3;
        int kb = (t >> 6) / 3;
        int kbase = kb * 32 + (lane >> 4) * 8;
        int n = f * 16 + (lane & 15);
        unsigned short hj[8], lj[8];
#pragma unroll
        for (int j = 0; j < 8; j++) {
            float v = (n < 40) ? W2[(size_t)(kbase + j) * 40 + n] : 0.f;
            unsigned short hb = f2bf(v);
            hj[j] = hb;
            lj[j] = f2bf(v - bf2f(hb));
        }
        ushort4 h0 = {hj[0], hj[1], hj[2], hj[3]}, h1 = {hj[4], hj[5], hj[6], hj[7]};
        ushort4 l0 = {lj[0], lj[1], lj[2], lj[3]}, l1 = {lj[4], lj[5], lj[6], lj[7]};
        ((ushort4*)Bh2)[t * 2] = h0; ((ushort4*)Bh2)[t * 2 + 1] = h1;
        ((ushort4*)Bl2)[t * 2] = l0; ((ushort4*)Bl2)[t * 2 + 1] = l1;
        return;
    }
    b -= p2B;
    {   // zero cnt + regp
        int i = b * 256 + threadIdx.x;
        if (i < zints) zbase[i] = 0;
    }
}

// ---- padded-CSR fill: single atomic = position alloc + degree count ----
__global__ void k_fill(const int* __restrict__ src, const int* __restrict__ dst, int E,
                       int* __restrict__ cnt, unsigned short* __restrict__ csr) {
    int e = blockIdx.x * blockDim.x + threadIdx.x;
    if (e >= E) return;
    int d = dst[e];
    int pos = atomicAdd(&cnt[d], 1);
    if (pos < CAP) csr[(size_t)d * CAP + pos] = (unsigned short)src[e];
}

// ---- MFMA GEMM: C[M][outN](bf16) = A[M][K] @ B (bf16x2 hi+lo), generic shape ----
template <int NF, int KB>
__global__ void k_mfma_gemm1(const unsigned short* __restrict__ Xh,
                             const unsigned short* __restrict__ Bh,
                             const unsigned short* __restrict__ Bl,
                             unsigned short* __restrict__ H0, int M) {
    const int K = KB * 32, N = NF * 16;
    int w = threadIdx.x >> 6, lane = threadIdx.x & 63;
    int m0 = blockIdx.x * 64 + w * 16;
    if (m0 >= M) return;
    float4v acc[NF] = {};
    const short8* A = (const short8*)(Xh + (size_t)(m0 + (lane & 15)) * K) + (lane >> 4);
    const short8* BH = ((const short8*)Bh) + lane;
    const short8* BL = ((const short8*)Bl) + lane;
    for (int kb = 0; kb < KB; kb++) {
        short8 a = A[kb * 4];
#pragma unroll
        for (int f = 0; f < NF; f++) {
            short8 bh = BH[(kb * NF + f) * 64];
            short8 bl = BL[(kb * NF + f) * 64];
            acc[f] = __builtin_amdgcn_mfma_f32_16x16x32_bf16(a, bh, acc[f], 0, 0, 0);
            acc[f] = __builtin_amdgcn_mfma_f32_16x16x32_bf16(a, bl, acc[f], 0, 0, 0);
        }
    }
    int row = (lane >> 4) * 4, col = lane & 15;
#pragma unroll
    for (int f = 0; f < NF; f++)
#pragma unroll
        for (int r = 0; r < 4; r++)
            H0[(size_t)(m0 + row + r) * N + f * 16 + col] = f2bf(acc[f][r]);
}

// ---- MFMA GEMM2: LG[M][48](fp32) = AGG1b[M][128] @ W2 (bf16 A, hi+lo B) ----
template <int NF, int KB>
__global__ void k_mfma_gemm2(const unsigned short* __restrict__ Ab,
                             const unsigned short* __restrict__ Bh,
                             const unsigned short* __restrict__ Bl,
                             float* __restrict__ LG, int M) {
    const int K = KB * 32, N = NF * 16;
    int w = threadIdx.x >> 6, lane = threadIdx.x & 63;
    int m0 = blockIdx.x * 64 + w * 16;
    if (m0 >= M) return;
    float4v acc[NF] = {};
    const short8* A = (const short8*)(Ab + (size_t)(m0 + (lane & 15)) * K) + (lane >> 4);
    const short8* BH = ((const short8*)Bh) + lane;
    const short8* BL = ((const short8*)Bl) + lane;
#pragma unroll
    for (int kb = 0; kb < KB; kb++) {
        short8 a = A[kb * 4];
#pragma unroll
        for (int f = 0; f < NF; f++) {
            short8 bh = BH[(kb * NF + f) * 64];
            short8 bl = BL[(kb * NF + f) * 64];
            acc[f] = __builtin_amdgcn_mfma_f32_16x16x32_bf16(a, bh, acc[f], 0, 0, 0);
            acc[f] = __builtin_amdgcn_mfma_f32_16x16x32_bf16(a, bl, acc[f], 0, 0, 0);
        }
    }
    int row = (lane >> 4) * 4, col = lane & 15;
#pragma unroll
    for (int f = 0; f < NF; f++)
#pragma unroll
        for (int r = 0; r < 4; r++)
            LG[(size_t)(m0 + row + r) * N + f * 16 + col] = acc[f][r];
}

// ---- fused: [agg blocks] layer-1 gather+bias+relu -> bf16 | [reg blocks] CSR count ----
__global__ void k_agg1_reg(const int* __restrict__ cnt, const unsigned short* __restrict__ csr,
                           const unsigned short* __restrict__ H, const float* __restrict__ b1,
                           unsigned* __restrict__ aggb,
                           const int* __restrict__ src, const int* __restrict__ dst, int E,
                           float* __restrict__ regp, int Nn, int aggBlocks) {
    if ((int)blockIdx.x < aggBlocks) {
        int wid = blockIdx.x * 4 + (threadIdx.x >> 6);
        int lane = threadIdx.x & 63;
        if (wid >= Nn) return;
        int len = min(cnt[wid], CAP);
        float dd = rsqrtf((float)len + 1.0f);
        const unsigned* H2 = (const unsigned*)H;   // bf16x2 per lane
        unsigned ph = H2[(size_t)wid * 64 + lane];
        float sw = dd * dd;
        float accx = bf2f((unsigned short)(ph & 0xffff)) * sw;
        float accy = bf2f((unsigned short)(ph >> 16)) * sw;   // self-loop
        const unsigned short* row = csr + (size_t)wid * CAP;
        int j = 0;
        for (; j + 3 < len; j += 4) {
            int s0 = row[j], s1 = row[j + 1], s2 = row[j + 2], s3 = row[j + 3];
            float w0 = rsqrtf((float)cnt[s0] + 1.0f) * dd;
            float w1 = rsqrtf((float)cnt[s1] + 1.0f) * dd;
            float w2 = rsqrtf((float)cnt[s2] + 1.0f) * dd;
            float w3 = rsqrtf((float)cnt[s3] + 1.0f) * dd;
            unsigned p0 = H2[(size_t)s0 * 64 + lane];
            unsigned p1 = H2[(size_t)s1 * 64 + lane];
            unsigned p2 = H2[(size_t)s2 * 64 + lane];
            unsigned p3 = H2[(size_t)s3 * 64 + lane];
            accx += w0 * bf2f((unsigned short)(p0 & 0xffff)) + w1 * bf2f((unsigned short)(p1 & 0xffff));
            accy += w0 * bf2f((unsigned short)(p0 >> 16))   + w1 * bf2f((unsigned short)(p1 >> 16));
            accx += w2 * bf2f((unsigned short)(p2 & 0xffff)) + w3 * bf2f((unsigned short)(p3 & 0xffff));
            accy += w2 * bf2f((unsigned short)(p2 >> 16))   + w3 * bf2f((unsigned short)(p3 >> 16));
        }
        for (; j < len; j++) {
            int s0 = row[j];
            float w0 = rsqrtf((float)cnt[s0] + 1.0f) * dd;
            unsigned p0 = H2[(size_t)s0 * 64 + lane];
            accx += w0 * bf2f((unsigned short)(p0 & 0xffff));
            accy += w0 * bf2f((unsigned short)(p0 >> 16));
        }
        float2 bb = ((const float2*)b1)[lane];
        float vx = accx + bb.x, vy = accy + bb.y;
        vx = vx > 0.f ? vx : 0.f;
        vy = vy > 0.f ? vy : 0.f;
        aggb[(size_t)wid * 64 + lane] = (unsigned)f2bf(vx) | ((unsigned)f2bf(vy) << 16);
    } else {
        int e = ((int)blockIdx.x - aggBlocks) * 256 + (int)threadIdx.x;
        int c = 0;
        if (e < E) {
            int s = src[e];
            unsigned d = (unsigned)dst[e];
            int len = min(cnt[s], CAP);
            const unsigned short* row = csr + (size_t)s * CAP;   // 256B-aligned
            for (int i = 0; i < len; i += 4) {
                uint2 v = *(const uint2*)(row + i);
                c += ((v.x & 0xffffu) == d) ? 1 : 0;
                c += ((v.x >> 16) == d && i + 1 < len) ? 1 : 0;
                c += ((v.y & 0xffffu) == d && i + 2 < len) ? 1 : 0;
                c += ((v.y >> 16) == d && i + 3 < len) ? 1 : 0;
            }
        }
#pragma unroll
        for (int off = 32; off; off >>= 1) c += __shfl_xor(c, off, 64);
        if ((threadIdx.x & 63) == 0 && c) atomicAdd(regp, (float)c);
    }
}

// ---- layer-2 gather aggregation + bias + log_softmax (LG stride 48) ----
__global__ void k_agg2_lsm(const int* __restrict__ cnt, const unsigned short* __restrict__ csr,
                           const float* __restrict__ LG, const float* __restrict__ b2,
                           const float* __restrict__ regp, float* __restrict__ out,
                           int Nn, int F) {
    int wid = (blockIdx.x * blockDim.x + threadIdx.x) >> 6;
    int lane = threadIdx.x & 63;
    if (wid >= Nn) return;
    int len = min(cnt[wid], CAP);
    float dd = rsqrtf((float)len + 1.0f);
    bool act = lane < F;
    float acc = act ? LG[(size_t)wid * 48 + lane] * dd * dd : 0.f;  // self-loop
    const unsigned short* row = csr + (size_t)wid * CAP;
    int j = 0;
    for (; j + 3 < len; j += 4) {
        int s0 = row[j], s1 = row[j + 1], s2 = row[j + 2], s3 = row[j + 3];
        float w0 = rsqrtf((float)cnt[s0] + 1.0f) * dd;
        float w1 = rsqrtf((float)cnt[s1] + 1.0f) * dd;
        float w2 = rsqrtf((float)cnt[s2] + 1.0f) * dd;
        float w3 = rsqrtf((float)cnt[s3] + 1.0f) * dd;
        float a0 = act ? LG[(size_t)s0 * 48 + lane] : 0.f;
        float a1 = act ? LG[(size_t)s1 * 48 + lane] : 0.f;
        float a2 = act ? LG[(size_t)s2 * 48 + lane] : 0.f;
        float a3 = act ? LG[(size_t)s3 * 48 + lane] : 0.f;
        acc += w0 * a0 + w1 * a1 + w2 * a2 + w3 * a3;
    }
    for (; j < len; j++) {
        int s0 = row[j];
        float w0 = rsqrtf((float)cnt[s0] + 1.0f) * dd;
        float a0 = act ? LG[(size_t)s0 * 48 + lane] : 0.f;
        acc += w0 * a0;
    }
    float v = act ? acc + b2[lane] : -1e30f;
    float m = v;
#pragma unroll
    for (int off = 32; off; off >>= 1) m = fmaxf(m, __shfl_xor(m, off, 64));
    float ex = act ? expf(v - m) : 0.f;
    float ssum = ex;
#pragma unroll
    for (int off = 32; off; off >>= 1) ssum += __shfl_xor(ssum, off, 64);
    if (act) out[(size_t)wid * F + lane] = v - m - logf(ssum);
    if (wid == 0 && lane == 0) out[(size_t)Nn * F] = regp[0];
}

extern "C" void kernel_launch(void* const* d_in, const int* in_sizes, int n_in,
                              void* d_out, int out_size, void* d_ws, size_t ws_size,
                              hipStream_t stream) {
    const float* x  = (const float*)d_in[0];
    const int*   ei = (const int*)d_in[1];
    const float* W1 = (const float*)d_in[2];
    const float* b1 = (const float*)d_in[3];
    const float* W2 = (const float*)d_in[4];
    const float* b2 = (const float*)d_in[5];
    float* out = (float*)d_out;

    const int FH   = in_sizes[3];            // 128
    const int FOUT = in_sizes[5];            // 40
    const int FIN  = in_sizes[2] / FH;       // 512
    const int Nn   = in_sizes[0] / FIN;      // 10000
    const int E    = in_sizes[1] / 2;        // 320000
    const int* src = ei;
    const int* dst = ei + E;

    // ---- workspace layout (bases verified 16B-aligned for short8 loads) ----
    int*   cnt  = (int*)d_ws;                                 // Nn
    float* regp = (float*)(cnt + Nn);                         // 16 (1 used)
    unsigned short* csr   = (unsigned short*)(regp + 16);     // Nn*CAP
    unsigned short* Xh    = csr + (size_t)Nn * CAP;           // Nn*FIN
    unsigned short* H0b   = Xh + (size_t)Nn * FIN;            // Nn*FH
    unsigned short* AGG1b = H0b + (size_t)Nn * FH;            // Nn*FH
    unsigned short* Bh1   = AGG1b + (size_t)Nn * FH;          // 16*8*64*8 = 65536
    unsigned short* Bl1   = Bh1 + 65536;
    unsigned short* Bh2   = Bl1 + 65536;                      // 4*3*64*8 = 6144
    unsigned short* Bl2   = Bh2 + 6144;
    float* LG0 = (float*)(Bl2 + 6144);                        // Nn*48

    // 1) fused prep
    int total4 = Nn * FIN / 4;                 // 1.28M
    int convB = (total4 + 255) / 256;          // 5000
    int p1B = (16 * 8 * 64) / 256;             // 32
    int p2B = (4 * 3 * 64 + 255) / 256;        // 3
    int zints = Nn + 16;
    int zB = (zints + 255) / 256;              // 40
    k_prep<<<convB + p1B + p2B + zB, 256, 0, stream>>>(
        x, Xh, total4, W1, Bh1, Bl1, W2, Bh2, Bl2, cnt, zints, convB, p1B, p2B);

    // 2) padded CSR fill (+degree)
    k_fill<<<(E + 255) / 256, 256, 0, stream>>>(src, dst, E, cnt, csr);

    // 3) H0(bf16) = X @ W1
    k_mfma_gemm1<8, 16><<<(Nn + 63) / 64, 256, 0, stream>>>(Xh, Bh1, Bl1, H0b, Nn);

    // 4) agg1 (+bias+relu -> bf16) fused with reg scan
    int aggBlocks = (Nn + 3) / 4;              // 2500
    int regBlocks = (E + 255) / 256;           // 1250
    k_agg1_reg<<<aggBlocks + regBlocks, 256, 0, stream>>>(
        cnt, csr, H0b, b1, (unsigned*)AGG1b, src, dst, E, regp, Nn, aggBlocks);

    // 5) LG(fp32, stride 48) = AGG1b @ W2
    k_mfma_gemm2<3, 4><<<(Nn + 63) / 64, 256, 0, stream>>>(AGG1b, Bh2, Bl2, LG0, Nn);

    // 6) out = log_softmax(gather(LG)+b2); out[N*F] = reg
    k_agg2_lsm<<<(Nn * 64 + 255) / 256, 256, 0, stream>>>(cnt, csr, LG0, b2, regp, out, Nn, FOUT);
}

// Round 8
// 194.938 us; speedup vs baseline: 1.5298x; 1.0326x over previous
//
#include <hip/hip_runtime.h>
#include <hip/hip_bf16.h>

// Problem: N=10000, E=320000, FIN=512, FH=128, FOUT=40 (derived from in_sizes).
// Padded-CSR pipeline (CAP=128 slots/node; deg ~ Poisson(32), overflow impossible):
//  1. k_prep  : zero cnt/regp + X->bf16 + pack W1(hi/lo) + pack W2(hi/lo, N padded 40->48)
//  2. k_fill  : one atomicAdd per edge = position alloc AND degree count
//  3. k_mfma_gemm1 : H0(bf16) = Xbf @ W1 (bf16x2 hi+lo) | [extra blocks] dinvf=rsqrt(cnt+1)
//  4. k_agg1_reg   : [agg blocks] AGG1b(bf16) = relu(gather(H0)+b1), 8-wide MLP
//                    [reg blocks] reg += count of dst[e] in csr-row src[e]
//  5. k_mfma_gemm2 : LGb(bf16, stride 48) = AGG1b @ W2
//  6. k_agg2_lsm   : out = log_softmax(gather(LGb)+b2); out[N*F] = reg
// reg identity: reg = sum_{(s,d) in E} A[d,s]; CSR-by-dst row s holds srcs of edges
// into s, so A[d,s] = #occurrences of d in row s.

#define CAP 128

typedef __attribute__((ext_vector_type(8))) short short8;   // 8 x bf16 (4 VGPRs)
typedef __attribute__((ext_vector_type(4))) float float4v;  // MFMA C/D

__device__ __forceinline__ unsigned short f2bf(float f) {
    __hip_bfloat16 b = __float2bfloat16(f);
    return *reinterpret_cast<unsigned short*>(&b);
}
__device__ __forceinline__ float bf2f(unsigned short u) {
    __hip_bfloat16 b = *reinterpret_cast<__hip_bfloat16*>(&u);
    return __bfloat162float(b);
}

// ---- fused prep: zero cnt/regp | conv X->bf16 | pack W1 hi/lo | pack W2 hi/lo ----
__global__ void k_prep(const float* __restrict__ x, unsigned short* __restrict__ xh, int total4,
                       const float* __restrict__ W1, unsigned short* __restrict__ Bh1,
                       unsigned short* __restrict__ Bl1,
                       const float* __restrict__ W2, unsigned short* __restrict__ Bh2,
                       unsigned short* __restrict__ Bl2,
                       int* __restrict__ zbase, int zints,
                       int convB, int p1B, int p2B) {
    int b = blockIdx.x;
    if (b < convB) {
        int i = b * 256 + threadIdx.x;
        if (i < total4) {
            float4 v = ((const float4*)x)[i];
            ushort4 h;
            h.x = f2bf(v.x); h.y = f2bf(v.y); h.z = f2bf(v.z); h.w = f2bf(v.w);
            ((ushort4*)xh)[i] = h;
        }
        return;
    }
    b -= convB;
    if (b < p1B) {   // pack W1: KB=16, NF=8, N=128
        int t = b * 256 + threadIdx.x;
        int lane = t & 63;
        int f = (t >> 6) % 8;
        int kb = (t >> 6) / 8;
        int kbase = kb * 32 + (lane >> 4) * 8;
        int n = f * 16 + (lane & 15);
        unsigned short hj[8], lj[8];
#pragma unroll
        for (int j = 0; j < 8; j++) {
            float v = W1[(size_t)(kbase + j) * 128 + n];
            unsigned short hb = f2bf(v);
            hj[j] = hb;
            lj[j] = f2bf(v - bf2f(hb));
        }
        ushort4 h0 = {hj[0], hj[1], hj[2], hj[3]}, h1 = {hj[4], hj[5], hj[6], hj[7]};
        ushort4 l0 = {lj[0], lj[1], lj[2], lj[3]}, l1 = {lj[4], lj[5], lj[6], lj[7]};
        ((ushort4*)Bh1)[t * 2] = h0; ((ushort4*)Bh1)[t * 2 + 1] = h1;
        ((ushort4*)Bl1)[t * 2] = l0; ((ushort4*)Bl1)[t * 2 + 1] = l1;
        return;
    }
    b -= p1B;
    if (b < p2B) {   // pack W2: KB=4, NF=3 (48 padded, real N=40)
        int t = b * 256 + threadIdx.x;
        if (t >= 4 * 3 * 64) return;
        int lane = t & 63;
        int f = (t >> 6) % 3;
        int kb = (t >> 6) / 3;
        int kbase = kb * 32 + (lane >> 4) * 8;
        int n = f * 16 + (lane & 15);
        unsigned short hj[8], lj[8];
#pragma unroll
        for (int j = 0; j < 8; j++) {
            float v = (n < 40) ? W2[(size_t)(kbase + j) * 40 + n] : 0.f;
            unsigned short hb = f2bf(v);
            hj[j] = hb;
            lj[j] = f2bf(v - bf2f(hb));
        }
        ushort4 h0 = {hj[0], hj[1], hj[2], hj[3]}, h1 = {hj[4], hj[5], hj[6], hj[7]};
        ushort4 l0 = {lj[0], lj[1], lj[2], lj[3]}, l1 = {lj[4], lj[5], lj[6], lj[7]};
        ((ushort4*)Bh2)[t * 2] = h0; ((ushort4*)Bh2)[t * 2 + 1] = h1;
        ((ushort4*)Bl2)[t * 2] = l0; ((ushort4*)Bl2)[t * 2 + 1] = l1;
        return;
    }
    b -= p2B;
    {   // zero cnt + regp
        int i = b * 256 + threadIdx.x;
        if (i < zints) zbase[i] = 0;
    }
}

// ---- padded-CSR fill: single atomic = position alloc + degree count ----
__global__ void k_fill(const int* __restrict__ src, const int* __restrict__ dst, int E,
                       int* __restrict__ cnt, unsigned short* __restrict__ csr) {
    int e = blockIdx.x * blockDim.x + threadIdx.x;
    if (e >= E) return;
    int d = dst[e];
    int pos = atomicAdd(&cnt[d], 1);
    if (pos < CAP) csr[(size_t)d * CAP + pos] = (unsigned short)src[e];
}

// ---- MFMA GEMM1 (+ piggyback dinvf blocks): H0(bf16) = Xh @ W1 ----
template <int NF, int KB>
__global__ void k_mfma_gemm1(const unsigned short* __restrict__ Xh,
                             const unsigned short* __restrict__ Bh,
                             const unsigned short* __restrict__ Bl,
                             unsigned short* __restrict__ H0, int M,
                             const int* __restrict__ cnt, float* __restrict__ dinvf,
                             int gemmBlocks) {
    if ((int)blockIdx.x >= gemmBlocks) {
        int i = ((int)blockIdx.x - gemmBlocks) * 256 + (int)threadIdx.x;
        if (i < M) dinvf[i] = rsqrtf((float)min(cnt[i], CAP) + 1.0f);
        return;
    }
    const int K = KB * 32, N = NF * 16;
    int w = threadIdx.x >> 6, lane = threadIdx.x & 63;
    int m0 = blockIdx.x * 64 + w * 16;
    if (m0 >= M) return;
    float4v acc[NF] = {};
    const short8* A = (const short8*)(Xh + (size_t)(m0 + (lane & 15)) * K) + (lane >> 4);
    const short8* BH = ((const short8*)Bh) + lane;
    const short8* BL = ((const short8*)Bl) + lane;
    for (int kb = 0; kb < KB; kb++) {
        short8 a = A[kb * 4];
#pragma unroll
        for (int f = 0; f < NF; f++) {
            short8 bh = BH[(kb * NF + f) * 64];
            short8 bl = BL[(kb * NF + f) * 64];
            acc[f] = __builtin_amdgcn_mfma_f32_16x16x32_bf16(a, bh, acc[f], 0, 0, 0);
            acc[f] = __builtin_amdgcn_mfma_f32_16x16x32_bf16(a, bl, acc[f], 0, 0, 0);
        }
    }
    int row = (lane >> 4) * 4, col = lane & 15;
#pragma unroll
    for (int f = 0; f < NF; f++)
#pragma unroll
        for (int r = 0; r < 4; r++)
            H0[(size_t)(m0 + row + r) * N + f * 16 + col] = f2bf(acc[f][r]);
}

// ---- MFMA GEMM2: LGb[M][48](bf16) = AGG1b[M][128] @ W2 ----
template <int NF, int KB>
__global__ void k_mfma_gemm2(const unsigned short* __restrict__ Ab,
                             const unsigned short* __restrict__ Bh,
                             const unsigned short* __restrict__ Bl,
                             unsigned short* __restrict__ LGb, int M) {
    const int K = KB * 32, N = NF * 16;
    int w = threadIdx.x >> 6, lane = threadIdx.x & 63;
    int m0 = blockIdx.x * 64 + w * 16;
    if (m0 >= M) return;
    float4v acc[NF] = {};
    const short8* A = (const short8*)(Ab + (size_t)(m0 + (lane & 15)) * K) + (lane >> 4);
    const short8* BH = ((const short8*)Bh) + lane;
    const short8* BL = ((const short8*)Bl) + lane;
#pragma unroll
    for (int kb = 0; kb < KB; kb++) {
        short8 a = A[kb * 4];
#pragma unroll
        for (int f = 0; f < NF; f++) {
            short8 bh = BH[(kb * NF + f) * 64];
            short8 bl = BL[(kb * NF + f) * 64];
            acc[f] = __builtin_amdgcn_mfma_f32_16x16x32_bf16(a, bh, acc[f], 0, 0, 0);
            acc[f] = __builtin_amdgcn_mfma_f32_16x16x32_bf16(a, bl, acc[f], 0, 0, 0);
        }
    }
    int row = (lane >> 4) * 4, col = lane & 15;
#pragma unroll
    for (int f = 0; f < NF; f++)
#pragma unroll
        for (int r = 0; r < 4; r++)
            LGb[(size_t)(m0 + row + r) * N + f * 16 + col] = f2bf(acc[f][r]);
}

// ---- fused: [agg blocks] layer-1 gather (8-wide MLP) | [reg blocks] CSR count ----
__global__ void k_agg1_reg(const int* __restrict__ cnt, const unsigned short* __restrict__ csr,
                           const float* __restrict__ dinvf,
                           const unsigned short* __restrict__ H, const float* __restrict__ b1,
                           unsigned* __restrict__ aggb,
                           const int* __restrict__ src, const int* __restrict__ dst, int E,
                           float* __restrict__ regp, int Nn, int aggBlocks) {
    if ((int)blockIdx.x < aggBlocks) {
        int wid = blockIdx.x * 4 + (threadIdx.x >> 6);
        int lane = threadIdx.x & 63;
        if (wid >= Nn) return;
        int len = min(cnt[wid], CAP);
        float dd = dinvf[wid];
        const unsigned* H2 = (const unsigned*)H;   // bf16x2 per lane
        unsigned ph = H2[(size_t)wid * 64 + lane];
        float sw = dd * dd;
        float accx = bf2f((unsigned short)(ph & 0xffff)) * sw;
        float accy = bf2f((unsigned short)(ph >> 16)) * sw;   // self-loop
        const unsigned short* row = csr + (size_t)wid * CAP;  // 256B-aligned
        int j = 0;
        for (; j + 8 <= len; j += 8) {
            uint4 idv = *(const uint4*)(row + j);             // 8 ids, one 16B load
            int s0 = idv.x & 0xffff, s1 = idv.x >> 16;
            int s2 = idv.y & 0xffff, s3 = idv.y >> 16;
            int s4 = idv.z & 0xffff, s5 = idv.z >> 16;
            int s6 = idv.w & 0xffff, s7 = idv.w >> 16;
            float w0 = dinvf[s0], w1 = dinvf[s1], w2 = dinvf[s2], w3 = dinvf[s3];
            float w4 = dinvf[s4], w5 = dinvf[s5], w6 = dinvf[s6], w7 = dinvf[s7];
            unsigned p0 = H2[(size_t)s0 * 64 + lane];
            unsigned p1 = H2[(size_t)s1 * 64 + lane];
            unsigned p2 = H2[(size_t)s2 * 64 + lane];
            unsigned p3 = H2[(size_t)s3 * 64 + lane];
            unsigned p4 = H2[(size_t)s4 * 64 + lane];
            unsigned p5 = H2[(size_t)s5 * 64 + lane];
            unsigned p6 = H2[(size_t)s6 * 64 + lane];
            unsigned p7 = H2[(size_t)s7 * 64 + lane];
            w0 *= dd; w1 *= dd; w2 *= dd; w3 *= dd;
            w4 *= dd; w5 *= dd; w6 *= dd; w7 *= dd;
            accx += w0 * bf2f((unsigned short)(p0 & 0xffff)) + w1 * bf2f((unsigned short)(p1 & 0xffff))
                  + w2 * bf2f((unsigned short)(p2 & 0xffff)) + w3 * bf2f((unsigned short)(p3 & 0xffff))
                  + w4 * bf2f((unsigned short)(p4 & 0xffff)) + w5 * bf2f((unsigned short)(p5 & 0xffff))
                  + w6 * bf2f((unsigned short)(p6 & 0xffff)) + w7 * bf2f((unsigned short)(p7 & 0xffff));
            accy += w0 * bf2f((unsigned short)(p0 >> 16)) + w1 * bf2f((unsigned short)(p1 >> 16))
                  + w2 * bf2f((unsigned short)(p2 >> 16)) + w3 * bf2f((unsigned short)(p3 >> 16))
                  + w4 * bf2f((unsigned short)(p4 >> 16)) + w5 * bf2f((unsigned short)(p5 >> 16))
                  + w6 * bf2f((unsigned short)(p6 >> 16)) + w7 * bf2f((unsigned short)(p7 >> 16));
        }
        for (; j < len; j++) {
            int s0 = row[j];
            float w0 = dinvf[s0] * dd;
            unsigned p0 = H2[(size_t)s0 * 64 + lane];
            accx += w0 * bf2f((unsigned short)(p0 & 0xffff));
            accy += w0 * bf2f((unsigned short)(p0 >> 16));
        }
        float2 bb = ((const float2*)b1)[lane];
        float vx = accx + bb.x, vy = accy + bb.y;
        vx = vx > 0.f ? vx : 0.f;
        vy = vy > 0.f ? vy : 0.f;
        aggb[(size_t)wid * 64 + lane] = (unsigned)f2bf(vx) | ((unsigned)f2bf(vy) << 16);
    } else {
        int e = ((int)blockIdx.x - aggBlocks) * 256 + (int)threadIdx.x;
        int c = 0;
        if (e < E) {
            int s = src[e];
            unsigned d = (unsigned)dst[e];
            int len = min(cnt[s], CAP);
            const unsigned short* row = csr + (size_t)s * CAP;   // 256B-aligned
            for (int i = 0; i < len; i += 8) {
                uint4 v = *(const uint4*)(row + i);
                c += ((v.x & 0xffffu) == d) ? 1 : 0;
                c += ((v.x >> 16) == d && i + 1 < len) ? 1 : 0;
                c += ((v.y & 0xffffu) == d && i + 2 < len) ? 1 : 0;
                c += ((v.y >> 16) == d && i + 3 < len) ? 1 : 0;
                c += ((v.z & 0xffffu) == d && i + 4 < len) ? 1 : 0;
                c += ((v.z >> 16) == d && i + 5 < len) ? 1 : 0;
                c += ((v.w & 0xffffu) == d && i + 6 < len) ? 1 : 0;
                c += ((v.w >> 16) == d && i + 7 < len) ? 1 : 0;
            }
        }
#pragma unroll
        for (int off = 32; off; off >>= 1) c += __shfl_xor(c, off, 64);
        if ((threadIdx.x & 63) == 0 && c) atomicAdd(regp, (float)c);
    }
}

// ---- layer-2 gather aggregation (bf16 LG, 8-wide) + bias + log_softmax ----
__global__ void k_agg2_lsm(const int* __restrict__ cnt, const unsigned short* __restrict__ csr,
                           const float* __restrict__ dinvf,
                           const unsigned short* __restrict__ LGb, const float* __restrict__ b2,
                           const float* __restrict__ regp, float* __restrict__ out,
                           int Nn, int F) {
    int wid = (blockIdx.x * blockDim.x + threadIdx.x) >> 6;
    int lane = threadIdx.x & 63;
    if (wid >= Nn) return;
    int len = min(cnt[wid], CAP);
    float dd = dinvf[wid];
    bool act = lane < F;
    float acc = act ? bf2f(LGb[(size_t)wid * 48 + lane]) * dd * dd : 0.f;  // self-loop
    const unsigned short* row = csr + (size_t)wid * CAP;
    int j = 0;
    for (; j + 8 <= len; j += 8) {
        uint4 idv = *(const uint4*)(row + j);
        int s0 = idv.x & 0xffff, s1 = idv.x >> 16;
        int s2 = idv.y & 0xffff, s3 = idv.y >> 16;
        int s4 = idv.z & 0xffff, s5 = idv.z >> 16;
        int s6 = idv.w & 0xffff, s7 = idv.w >> 16;
        float w0 = dinvf[s0], w1 = dinvf[s1], w2 = dinvf[s2], w3 = dinvf[s3];
        float w4 = dinvf[s4], w5 = dinvf[s5], w6 = dinvf[s6], w7 = dinvf[s7];
        float a0 = act ? bf2f(LGb[(size_t)s0 * 48 + lane]) : 0.f;
        float a1 = act ? bf2f(LGb[(size_t)s1 * 48 + lane]) : 0.f;
        float a2 = act ? bf2f(LGb[(size_t)s2 * 48 + lane]) : 0.f;
        float a3 = act ? bf2f(LGb[(size_t)s3 * 48 + lane]) : 0.f;
        float a4 = act ? bf2f(LGb[(size_t)s4 * 48 + lane]) : 0.f;
        float a5 = act ? bf2f(LGb[(size_t)s5 * 48 + lane]) : 0.f;
        float a6 = act ? bf2f(LGb[(size_t)s6 * 48 + lane]) : 0.f;
        float a7 = act ? bf2f(LGb[(size_t)s7 * 48 + lane]) : 0.f;
        acc += (w0 * dd) * a0 + (w1 * dd) * a1 + (w2 * dd) * a2 + (w3 * dd) * a3
             + (w4 * dd) * a4 + (w5 * dd) * a5 + (w6 * dd) * a6 + (w7 * dd) * a7;
    }
    for (; j < len; j++) {
        int s0 = row[j];
        float w0 = dinvf[s0] * dd;
        float a0 = act ? bf2f(LGb[(size_t)s0 * 48 + lane]) : 0.f;
        acc += w0 * a0;
    }
    float v = act ? acc + b2[lane] : -1e30f;
    float m = v;
#pragma unroll
    for (int off = 32; off; off >>= 1) m = fmaxf(m, __shfl_xor(m, off, 64));
    float ex = act ? expf(v - m) : 0.f;
    float ssum = ex;
#pragma unroll
    for (int off = 32; off; off >>= 1) ssum += __shfl_xor(ssum, off, 64);
    if (act) out[(size_t)wid * F + lane] = v - m - logf(ssum);
    if (wid == 0 && lane == 0) out[(size_t)Nn * F] = regp[0];
}

extern "C" void kernel_launch(void* const* d_in, const int* in_sizes, int n_in,
                              void* d_out, int out_size, void* d_ws, size_t ws_size,
                              hipStream_t stream) {
    const float* x  = (const float*)d_in[0];
    const int*   ei = (const int*)d_in[1];
    const float* W1 = (const float*)d_in[2];
    const float* b1 = (const float*)d_in[3];
    const float* W2 = (const float*)d_in[4];
    const float* b2 = (const float*)d_in[5];
    float* out = (float*)d_out;

    const int FH   = in_sizes[3];            // 128
    const int FOUT = in_sizes[5];            // 40
    const int FIN  = in_sizes[2] / FH;       // 512
    const int Nn   = in_sizes[0] / FIN;      // 10000
    const int E    = in_sizes[1] / 2;        // 320000
    const int* src = ei;
    const int* dst = ei + E;

    // ---- workspace layout (all bases 16B-aligned; csr rows 256B-aligned) ----
    int*   cnt  = (int*)d_ws;                                 // Nn
    float* regp = (float*)(cnt + Nn);                         // 16 (1 used)
    unsigned short* csr   = (unsigned short*)(regp + 16);     // Nn*CAP
    unsigned short* Xh    = csr + (size_t)Nn * CAP;           // Nn*FIN
    unsigned short* H0b   = Xh + (size_t)Nn * FIN;            // Nn*FH
    unsigned short* AGG1b = H0b + (size_t)Nn * FH;            // Nn*FH
    unsigned short* Bh1   = AGG1b + (size_t)Nn * FH;          // 16*8*64*8 = 65536
    unsigned short* Bl1   = Bh1 + 65536;
    unsigned short* Bh2   = Bl1 + 65536;                      // 4*3*64*8 = 6144
    unsigned short* Bl2   = Bh2 + 6144;
    float* dinvf = (float*)(Bl2 + 6144);                      // Nn
    unsigned short* LGb = (unsigned short*)(dinvf + Nn);      // Nn*48 + 64 pad

    // 1) fused prep
    int total4 = Nn * FIN / 4;                 // 1.28M
    int convB = (total4 + 255) / 256;          // 5000
    int p1B = (16 * 8 * 64) / 256;             // 32
    int p2B = (4 * 3 * 64 + 255) / 256;        // 3
    int zints = Nn + 16;
    int zB = (zints + 255) / 256;              // 40
    k_prep<<<convB + p1B + p2B + zB, 256, 0, stream>>>(
        x, Xh, total4, W1, Bh1, Bl1, W2, Bh2, Bl2, cnt, zints, convB, p1B, p2B);

    // 2) padded CSR fill (+degree)
    k_fill<<<(E + 255) / 256, 256, 0, stream>>>(src, dst, E, cnt, csr);

    // 3) H0(bf16) = X @ W1  | piggyback: dinvf = rsqrt(min(cnt,CAP)+1)
    int gemmB = (Nn + 63) / 64;                // 157
    int dinvB = (Nn + 255) / 256;              // 40
    k_mfma_gemm1<8, 16><<<gemmB + dinvB, 256, 0, stream>>>(
        Xh, Bh1, Bl1, H0b, Nn, cnt, dinvf, gemmB);

    // 4) agg1 (+bias+relu -> bf16) fused with reg scan, 8-wide MLP
    int aggBlocks = (Nn + 3) / 4;              // 2500
    int regBlocks = (E + 255) / 256;           // 1250
    k_agg1_reg<<<aggBlocks + regBlocks, 256, 0, stream>>>(
        cnt, csr, dinvf, H0b, b1, (unsigned*)AGG1b, src, dst, E, regp, Nn, aggBlocks);

    // 5) LGb(bf16, stride 48) = AGG1b @ W2
    k_mfma_gemm2<3, 4><<<(Nn + 63) / 64, 256, 0, stream>>>(AGG1b, Bh2, Bl2, LGb, Nn);

    // 6) out = log_softmax(gather(LGb)+b2); out[N*F] = reg
    k_agg2_lsm<<<(Nn * 64 + 255) / 256, 256, 0, stream>>>(
        cnt, csr, dinvf, LGb, b2, regp, out, Nn, FOUT);
}